// Round 13
// baseline (203.942 us; speedup 1.0000x reference)
//
#include <hip/hip_runtime.h>
#include <hip/hip_bf16.h>
#include <cstdint>
#include <cstddef>

// Problem constants (shapes fixed by the reference)
#define NN      10000      // nodes (M == N == 10000)
#define DD      256        // feature dim
#define KSTEPS  313        // ceil(10016/32) K-steps of 32
#define MB256   40         // ceil(10000/256) m-blocks for big GEMM (BM=256)
#define KSPLIT  6          // 40*6 = 240 blocks = 8 XCDs x 30, 1 block/CU (8 waves)

typedef __bf16 bf16x8 __attribute__((ext_vector_type(8)));
typedef float  f32x4  __attribute__((ext_vector_type(4)));

// ---- workspace layout (bytes) ----
#define XG_OFF   0ull
#define XG_SIZE  (32ull * 10000 * 16)        // [q=kb*4+g][row] 16B chunks (bf16 X, MFMA-A layout)
#define WG_OFF   (XG_OFF + XG_SIZE)
#define WG_SIZE  (32ull * 256 * 16)          // [q][n] chunks (bf16 W, MFMA-B layout)
#define INP_OFF  (WG_OFF + WG_SIZE)
#define INP_SIZE (10000ull * 256 * 4)        // inp = X@W, f32
#define E_OFF    (INP_OFF + INP_SIZE)
#define E_SIZE   (10016ull * 4)
#define HS_OFF   (E_OFF + E_SIZE)
#define HS_SIZE  (10016ull * 4)
#define G_OFF    (HS_OFF + HS_SIZE)
#define G_SIZE   (10016ull * 4)
#define YG_OFF   (G_OFF + G_SIZE + 256ull)   // keep 256B alignment
#define YG_SIZE  (320ull * 1088 * 16)        // [kb32][chunk]; kb 313..319 zero pads (2-ahead staging safe)
#define PN_OFF   (YG_OFF + YG_SIZE)
#define PN_SIZE  ((size_t)KSPLIT * 10000 * 272 * 4)  // per-kc partials: 256 numer cols + den at col 256

// async global(16B) -> LDS copy; dest = wave-uniform base + lane*16
__device__ __forceinline__ void gl_lds16(const void* g, void* lds) {
    __builtin_amdgcn_global_load_lds(
        (const __attribute__((address_space(1))) unsigned int*)g,
        (__attribute__((address_space(3))) unsigned int*)lds,
        16, 0, 0);
}

// ---------------- K0a: build XG (bf16 X in MFMA-A chunk layout) ----------------
__global__ __launch_bounds__(256) void k_build_xg(const float* __restrict__ X,
                                                  bf16x8* __restrict__ XG) {
    int idx = blockIdx.x * 256 + threadIdx.x;   // 0..319999
    int row = idx >> 5;
    int q   = idx & 31;
    const float* src = X + row * 256 + q * 8;
    bf16x8 v;
#pragma unroll
    for (int j = 0; j < 8; ++j) v[j] = (__bf16)src[j];
    XG[q * 10000 + row] = v;
}

// ---------------- K0b: build WG (bf16 W in MFMA-B chunk layout) ----------------
__global__ __launch_bounds__(256) void k_build_wg(const float* __restrict__ W,
                                                  bf16x8* __restrict__ WG) {
    int e = blockIdx.x * 256 + threadIdx.x;     // 0..8191
    int q = e >> 8;
    int n = e & 255;
    bf16x8 v;
#pragma unroll
    for (int j = 0; j < 8; ++j) v[j] = (__bf16)W[(q * 8 + j) * 256 + n];
    WG[e] = v;
}

// ---------------- K1: inp = X@W (MFMA), fused tanh/e/hsum (LDS cross-wave reduce) ----------------
__global__ __launch_bounds__(256) void k_gemm1(const bf16x8* __restrict__ XG,
                                               const bf16x8* __restrict__ WG,
                                               const float* __restrict__ bvec,
                                               const float* __restrict__ avec,
                                               float* __restrict__ inp,
                                               float* __restrict__ evec,
                                               float* __restrict__ hsumv) {
    __shared__ bf16x8 Ash[320];    // (g*80 + r)
    __shared__ bf16x8 Bsh[1024];   // (g*256 + n)
    __shared__ float ePart[4][80];
    __shared__ float hPart[4][80];
    int tid = threadIdx.x, wid = tid >> 6, lane = tid & 63;
    int l15 = lane & 15, l4 = lane >> 4;
    int mb = blockIdx.x;

    f32x4 acc[4][5];
#pragma unroll
    for (int c = 0; c < 4; ++c)
#pragma unroll
        for (int rt = 0; rt < 5; ++rt) acc[c][rt] = f32x4{0.f, 0.f, 0.f, 0.f};

    for (int kb = 0; kb < 8; ++kb) {
        for (int rr = wid; rr < 5; rr += 4) {
            int c = rr * 64 + lane;
            int g = c / 80, r = c - g * 80;
            gl_lds16(XG + ((kb * 4 + g) * 10000 + mb * 80 + r), (char*)Ash + rr * 1024);
        }
        for (int rr = wid; rr < 16; rr += 4)
            gl_lds16(WG + kb * 1024 + rr * 64 + lane, (char*)Bsh + rr * 1024);
        __syncthreads();

        bf16x8 af[5];
#pragma unroll
        for (int rt = 0; rt < 5; ++rt) af[rt] = Ash[l4 * 80 + rt * 16 + l15];
#pragma unroll
        for (int c = 0; c < 4; ++c) {
            bf16x8 bf = Bsh[l4 * 256 + (wid * 4 + c) * 16 + l15];
#pragma unroll
            for (int rt = 0; rt < 5; ++rt)
                acc[c][rt] = __builtin_amdgcn_mfma_f32_16x16x32_bf16(af[rt], bf, acc[c][rt], 0, 0, 0);
        }
        __syncthreads();
    }

    float pe[5][4], ph[5][4];
#pragma unroll
    for (int rt = 0; rt < 5; ++rt)
#pragma unroll
        for (int rg = 0; rg < 4; ++rg) { pe[rt][rg] = 0.f; ph[rt][rg] = 0.f; }

#pragma unroll
    for (int c = 0; c < 4; ++c) {
        int col = (wid * 4 + c) * 16 + l15;
        float av = avec[col];
        float bv = bvec[col];
#pragma unroll
        for (int rt = 0; rt < 5; ++rt) {
#pragma unroll
            for (int rg = 0; rg < 4; ++rg) {
                int row = mb * 80 + rt * 16 + l4 * 4 + rg;
                float v = acc[c][rt][rg];            // inp excludes bias (per reference)
                inp[row * 256 + col] = v;
                float h = tanhf(v + bv);
                pe[rt][rg] += h * av;
                ph[rt][rg] += h;
            }
        }
    }
#pragma unroll
    for (int rt = 0; rt < 5; ++rt) {
#pragma unroll
        for (int rg = 0; rg < 4; ++rg) {
            float se = pe[rt][rg], sh = ph[rt][rg];
#pragma unroll
            for (int m = 1; m < 16; m <<= 1) {
                se += __shfl_xor(se, m);
                sh += __shfl_xor(sh, m);
            }
            if (l15 == 0) {
                int lr = rt * 16 + l4 * 4 + rg;   // 0..79
                ePart[wid][lr] = se;
                hPart[wid][lr] = sh;
            }
        }
    }
    __syncthreads();
    if (tid < 80) {
        float e = ePart[0][tid] + ePart[1][tid] + ePart[2][tid] + ePart[3][tid];
        float h = hPart[0][tid] + hPart[1][tid] + hPart[2][tid] + hPart[3][tid];
        evec[mb * 80 + tid] = e;
        hsumv[mb * 80 + tid] = h;
    }
}

// ---------------- K2: global max of e over valid nodes, then g = exp(e-gmax) ----------------
__global__ __launch_bounds__(1024) void k_softmax_g(const float* __restrict__ evec,
                                                    const float* __restrict__ hsumv,
                                                    float* __restrict__ gv) {
    __shared__ float red[1024];
    int tid = threadIdx.x;
    float m = -3.0e38f;
    for (int i = tid; i < NN; i += 1024)
        if (hsumv[i] != 0.0f) m = fmaxf(m, evec[i]);
    red[tid] = m;
    __syncthreads();
    for (int s = 512; s > 0; s >>= 1) {
        if (tid < s) red[tid] = fmaxf(red[tid], red[tid + s]);
        __syncthreads();
    }
    float gmax = red[0];
    if (gmax < -1.0e37f) gmax = 0.0f;
    for (int i = tid; i < 10016; i += 1024) {
        float g = 0.0f;
        if (i < NN && hsumv[i] != 0.0f) g = expf(evec[i] - gmax);
        gv[i] = g;
    }
}

// ---------------- K3: build YG = pre-chunked bf16 B tiles for the big GEMM ----------------
// grid 320: kb >= 313 hits the k<NN guard everywhere -> zero pads
__global__ __launch_bounds__(256) void k_build_yg(const float* __restrict__ inp,
                                                  const float* __restrict__ gv,
                                                  bf16x8* __restrict__ YG) {
    int kb = blockIdx.x;   // 0..319
    for (int c = threadIdx.x; c < 1088; c += 256) {
        int gq = c / 272, n = c - gq * 272;
        int k0 = kb * 32 + gq * 8;
        bf16x8 v;
#pragma unroll
        for (int j = 0; j < 8; ++j) {
            int k = k0 + j;
            float val = 0.0f;
            if (k < NN) {
                float gk = gv[k];
                if (n < 256) val = gk * inp[k * 256 + n];
                else if (n == 256) val = gk;
            }
            v[j] = (__bf16)val;
        }
        YG[kb * 1088 + c] = v;
    }
}

// ---- int32 {0,1} pair-of-int4 -> bf16x8 {0,1} fragment ----
__device__ __forceinline__ bf16x8 cvt_adj(int4 a, int4 b) {
    union { bf16x8 v; unsigned int u[4]; } r;
    r.u[0] = (a.x > 0 ? 0x3F80u : 0u) | (a.y > 0 ? 0x3F800000u : 0u);
    r.u[1] = (a.z > 0 ? 0x3F80u : 0u) | (a.w > 0 ? 0x3F800000u : 0u);
    r.u[2] = (b.x > 0 ? 0x3F80u : 0u) | (b.y > 0 ? 0x3F800000u : 0u);
    r.u[3] = (b.z > 0 ? 0x3F80u : 0u) | (b.w > 0 ? 0x3F800000u : 0u);
    return r.v;
}

// ---------------- K4: num_kc = adj @ Y  (BURST-A + 2-AHEAD-B) ----------------
// The R1-R12 invariant (~150us) is attacked on the two untouched axes:
// (1) A-read DRAM granularity: loads for 4 K-steps batched back-to-back -> each adj
//     row read as ONE 512-B contiguous burst per 4 steps (was: 128-B granules, ~us
//     apart, at 40-KB row stride -> poor DRAM efficiency on the 400-MB stream).
// (2) B staged TWO steps ahead in 3 LDS buffers; every vmcnt retires only ops
//     >=1.5 steps old (j<3: vmcnt(3); j=3: vmcnt(19) keeps fresh A16+stage3).
// BM=256: 8 waves x 32 rows (2 row-tiles), 17 col-tiles, BK=32; 512 thr, 1 block/CU,
// 240 blocks = 8 XCDs x 30 chunked kc-major swizzle (YG slice L2-resident).
__global__ __launch_bounds__(512, 2) void k_attn_gemm(const int* __restrict__ adj,
                                                      const bf16x8* __restrict__ YG,
                                                      float* __restrict__ pnum) {
    __shared__ bf16x8 Bsh[3][1088];   // 3 x 17408 B = 52224 B
    int tid = threadIdx.x, wid = tid >> 6, lane = tid & 63;
    int l15 = lane & 15, l4 = lane >> 4;

    // chunked XCD swizzle: 240 = 8*30 exact; kc-major -> XCD x covers <=2 kc slices
    int phys = blockIdx.x;
    int logical = (phys & 7) * 30 + (phys >> 3);
    int kc = logical / MB256, mb = logical % MB256;
    int s0 = (kc * KSTEPS) / KSPLIT, s1 = ((kc + 1) * KSTEPS) / KSPLIT;   // size 52 or 53

    // A addressing: wave owns rows mb*256 + wid*32 .. +31 (2 row-tiles of 16)
    int r0w = mb * 256 + wid * 32;
    const int* pA = adj + (size_t)min(r0w + l15, NN - 1) * 10000;        // row-tile 0
    const int* pB = adj + (size_t)min(r0w + 16 + l15, NN - 1) * 10000;   // row-tile 1
    int kgrp = l4 * 8;

    f32x4 acc[2][17];
#pragma unroll
    for (int t = 0; t < 2; ++t)
#pragma unroll
        for (int ct = 0; ct < 17; ++ct) acc[t][ct] = f32x4{0.f, 0.f, 0.f, 0.f};

    int4 aA[16];   // 4 steps x 2 row-tiles x 2 int4 — one 512-B burst per row per batch

    auto stageB = [&](int sTile, int bufIdx) {   // 3 gl_lds per wave (uniform count)
        const bf16x8* src = YG + (size_t)sTile * 1088;
        char* dst = (char*)&Bsh[bufIdx][0];
        gl_lds16(src + (2 * wid) * 64 + lane, dst + (2 * wid) * 1024);
        gl_lds16(src + (2 * wid + 1) * 64 + lane, dst + (2 * wid + 1) * 1024);
        gl_lds16(src + 16 * 64 + lane, dst + 16 * 1024);   // row 16: all waves, same data
    };
    auto loadBatch = [&](int S) {   // steps S..S+3: 16 back-to-back int4 loads
#pragma unroll
        for (int j = 0; j < 4; ++j) {
            int kk = min((S + j) * 32 + kgrp, 9992);   // clamp safe: B is 0 for k>=NN
            const int4* p0 = (const int4*)(pA + kk);
            const int4* p1 = (const int4*)(pB + kk);
            aA[j * 4 + 0] = p0[0]; aA[j * 4 + 1] = p0[1];
            aA[j * 4 + 2] = p1[0]; aA[j * 4 + 3] = p1[1];
        }
    };
    auto compute = [&](bf16x8 fa0, bf16x8 fa1, int b) {
#pragma unroll
        for (int ct = 0; ct < 17; ++ct) {
            bf16x8 fb = Bsh[b][l4 * 272 + ct * 16 + l15];
            acc[0][ct] = __builtin_amdgcn_mfma_f32_16x16x32_bf16(fa0, fb, acc[0][ct], 0, 0, 0);
            acc[1][ct] = __builtin_amdgcn_mfma_f32_16x16x32_bf16(fa1, fb, acc[1][ct], 0, 0, 0);
        }
    };

    // ---- prologue: A-batch(s0..s0+3); B(s0), B(s0+1) ----
    loadBatch(s0);
    int b0 = s0 % 3;
    int b1 = b0 + 1; if (b1 > 2) b1 -= 3;
    int b2 = b1 + 1; if (b2 > 2) b2 -= 3;
    stageB(s0, b0);
    stageB(s0 + 1, b1);
    __builtin_amdgcn_sched_barrier(0);
    asm volatile("s_waitcnt vmcnt(3)" ::: "memory");   // retire A + B(s0); keep B(s0+1)
    __builtin_amdgcn_s_barrier();

    // ---- main loop: groups of 4 steps; straight-line body, static A indexing ----
    int G = s0;
    while (G + 4 <= s1) {
        // j=0: compute buf b0 (=B(G)); stage B(G+2) -> b2
        {
            stageB(G + 2, b2);
            __builtin_amdgcn_sched_barrier(0);
            bf16x8 fa0 = cvt_adj(aA[0], aA[1]);
            bf16x8 fa1 = cvt_adj(aA[2], aA[3]);
            compute(fa0, fa1, b0);
            asm volatile("s_waitcnt vmcnt(3)" ::: "memory");   // retire B(G+1); keep B(G+2)
            __builtin_amdgcn_s_barrier();
        }
        // j=1: compute b1 (=B(G+1)); stage B(G+3) -> b0
        {
            stageB(G + 3, b0);
            __builtin_amdgcn_sched_barrier(0);
            bf16x8 fa0 = cvt_adj(aA[4], aA[5]);
            bf16x8 fa1 = cvt_adj(aA[6], aA[7]);
            compute(fa0, fa1, b1);
            asm volatile("s_waitcnt vmcnt(3)" ::: "memory");   // retire B(G+2); keep B(G+3)
            __builtin_amdgcn_s_barrier();
        }
        // j=2: compute b2 (=B(G+2)); stage B(G+4) -> b1
        {
            stageB(G + 4, b1);
            __builtin_amdgcn_sched_barrier(0);
            bf16x8 fa0 = cvt_adj(aA[8], aA[9]);
            bf16x8 fa1 = cvt_adj(aA[10], aA[11]);
            compute(fa0, fa1, b2);
            asm volatile("s_waitcnt vmcnt(3)" ::: "memory");   // retire B(G+3); keep B(G+4)
            __builtin_amdgcn_s_barrier();
        }
        // j=3: compute b0 (=B(G+3)); stage B(G+5) -> b2; issue next A-batch (kept in flight)
        {
            stageB(G + 5, b2);
            __builtin_amdgcn_sched_barrier(0);
            bf16x8 fa0 = cvt_adj(aA[12], aA[13]);
            bf16x8 fa1 = cvt_adj(aA[14], aA[15]);
            loadBatch(G + 4);                                   // after cvt reads (WAR)
            __builtin_amdgcn_sched_barrier(0);
            compute(fa0, fa1, b0);
            asm volatile("s_waitcnt vmcnt(19)" ::: "memory");  // retire B(G+4); keep B(G+5)+A16
            __builtin_amdgcn_s_barrier();
        }
        G += 4;
        b0 = b0 + 1; if (b0 > 2) b0 -= 3;
        b1 = b0 + 1; if (b1 > 2) b1 -= 3;
        b2 = b1 + 1; if (b2 > 2) b2 -= 3;
    }
    if (G < s1) {   // tail (size 53 slice only, T=1): B(G) staged+retired; A in aA[0..3]
        bf16x8 fa0 = cvt_adj(aA[0], aA[1]);
        bf16x8 fa1 = cvt_adj(aA[2], aA[3]);
        compute(fa0, fa1, b0);
    }

    // ---- epilogue: plain stores to per-kc partial buffer ----
    float* base = pnum + (size_t)kc * 10000 * 272;
#pragma unroll
    for (int t = 0; t < 2; ++t) {
#pragma unroll
        for (int ct = 0; ct < 17; ++ct) {
            int col = ct * 16 + l15;
#pragma unroll
            for (int rg = 0; rg < 4; ++rg) {
                int row = r0w + t * 16 + l4 * 4 + rg;
                if (row < NN) base[(size_t)row * 272 + col] = acc[t][ct][rg];
            }
        }
    }
}

// ---------------- K5: out = (sum_kc num_kc) / max(sum_kc den_kc, 1e-30) ----------------
__global__ __launch_bounds__(256) void k_finalize(const float* __restrict__ pnum,
                                                  float* __restrict__ out) {
    int idx = blockIdx.x * 256 + threadIdx.x;   // 0..639999 (float4 units)
    int i = idx >> 6, q = idx & 63;
    float4 sv = {0.f, 0.f, 0.f, 0.f};
    float den = 0.f;
#pragma unroll
    for (int kc = 0; kc < KSPLIT; ++kc) {
        const float* row = pnum + ((size_t)kc * 10000 + i) * 272;
        float4 v = ((const float4*)row)[q];
        sv.x += v.x; sv.y += v.y; sv.z += v.z; sv.w += v.w;
        den += row[256];
    }
    float r = 1.0f / fmaxf(den, 1e-30f);
    float4 o;
    o.x = sv.x * r; o.y = sv.y * r; o.z = sv.z * r; o.w = sv.w * r;
    ((float4*)(out + (size_t)i * 256))[q] = o;
}

extern "C" void kernel_launch(void* const* d_in, const int* in_sizes, int n_in,
                              void* d_out, int out_size, void* d_ws, size_t ws_size,
                              hipStream_t stream) {
    const float* X    = (const float*)d_in[0];
    const int*   adj  = (const int*)d_in[1];
    const float* W    = (const float*)d_in[3];
    const float* bvec = (const float*)d_in[4];
    const float* avec = (const float*)d_in[5];
    float* out = (float*)d_out;

    char* ws = (char*)d_ws;
    bf16x8* XG   = (bf16x8*)(ws + XG_OFF);
    bf16x8* WG   = (bf16x8*)(ws + WG_OFF);
    float*  inp  = (float*)(ws + INP_OFF);
    float*  evec = (float*)(ws + E_OFF);
    float*  hsv  = (float*)(ws + HS_OFF);
    float*  gv   = (float*)(ws + G_OFF);
    bf16x8* YG   = (bf16x8*)(ws + YG_OFF);
    float*  pnum = (float*)(ws + PN_OFF);

    k_build_xg<<<1250, 256, 0, stream>>>(X, XG);
    k_build_wg<<<32, 256, 0, stream>>>(W, WG);
    k_gemm1<<<125, 256, 0, stream>>>(XG, WG, bvec, avec, inp, evec, hsv);
    k_softmax_g<<<1, 1024, 0, stream>>>(evec, hsv, gv);
    k_build_yg<<<320, 256, 0, stream>>>(inp, gv, YG);
    k_attn_gemm<<<MB256 * KSPLIT, 512, 0, stream>>>(adj, YG, pnum);
    k_finalize<<<2500, 256, 0, stream>>>(pnum, out);
}

// Round 14
// 196.609 us; speedup vs baseline: 1.0373x; 1.0373x over previous
//
#include <hip/hip_runtime.h>
#include <hip/hip_bf16.h>
#include <cstdint>
#include <cstddef>

// Problem constants (shapes fixed by the reference)
#define NN      10000      // nodes (M == N == 10000)
#define DD      256        // feature dim
#define KSTEPS  313        // ceil(10016/32) K-steps of 32
#define MB2     79         // ceil(10000/128) m-blocks for big GEMM (BM=128)
#define KSPLIT  6          // 79*6 = 474 blocks, 2/CU

typedef __bf16 bf16x8 __attribute__((ext_vector_type(8)));
typedef float  f32x4  __attribute__((ext_vector_type(4)));
typedef float  f32x16 __attribute__((ext_vector_type(16)));

// ---- workspace layout (bytes) ----
#define XG_OFF   0ull
#define XG_SIZE  (32ull * 10000 * 16)        // [q=kb*4+g][row] 16B chunks (bf16 X, MFMA-A layout)
#define WG_OFF   (XG_OFF + XG_SIZE)
#define WG_SIZE  (32ull * 256 * 16)          // [q][n] chunks (bf16 W, MFMA-B layout)
#define INP_OFF  (WG_OFF + WG_SIZE)
#define INP_SIZE (10000ull * 256 * 4)        // inp = X@W, f32
#define E_OFF    (INP_OFF + INP_SIZE)
#define E_SIZE   (10016ull * 4)
#define HS_OFF   (E_OFF + E_SIZE)
#define HS_SIZE  (10016ull * 4)
#define G_OFF    (HS_OFF + HS_SIZE)
#define G_SIZE   (10016ull * 4)
#define YG_OFF   (G_OFF + G_SIZE + 256ull)   // keep 256B alignment
#define YG_SIZE  (320ull * 1152 * 16)        // [kb32][oct0..3][col0..287] chunks; kb>=313 zero pads
#define PN_OFF   (YG_OFF + YG_SIZE)
#define PN_SIZE  ((size_t)KSPLIT * 10000 * 272 * 4)  // per-kc partials: 256 numer cols + den at col 256

// async global(16B) -> LDS copy; dest = wave-uniform base + lane*16
__device__ __forceinline__ void gl_lds16(const void* g, void* lds) {
    __builtin_amdgcn_global_load_lds(
        (const __attribute__((address_space(1))) unsigned int*)g,
        (__attribute__((address_space(3))) unsigned int*)lds,
        16, 0, 0);
}

// ---------------- K0a: build XG (bf16 X in MFMA-A chunk layout) ----------------
__global__ __launch_bounds__(256) void k_build_xg(const float* __restrict__ X,
                                                  bf16x8* __restrict__ XG) {
    int idx = blockIdx.x * 256 + threadIdx.x;   // 0..319999
    int row = idx >> 5;
    int q   = idx & 31;
    const float* src = X + row * 256 + q * 8;
    bf16x8 v;
#pragma unroll
    for (int j = 0; j < 8; ++j) v[j] = (__bf16)src[j];
    XG[q * 10000 + row] = v;
}

// ---------------- K0b: build WG (bf16 W in MFMA-B chunk layout) ----------------
__global__ __launch_bounds__(256) void k_build_wg(const float* __restrict__ W,
                                                  bf16x8* __restrict__ WG) {
    int e = blockIdx.x * 256 + threadIdx.x;     // 0..8191
    int q = e >> 8;
    int n = e & 255;
    bf16x8 v;
#pragma unroll
    for (int j = 0; j < 8; ++j) v[j] = (__bf16)W[(q * 8 + j) * 256 + n];
    WG[e] = v;
}

// ---------------- K1: inp = X@W (MFMA), fused tanh/e/hsum (LDS cross-wave reduce) ----------------
__global__ __launch_bounds__(256) void k_gemm1(const bf16x8* __restrict__ XG,
                                               const bf16x8* __restrict__ WG,
                                               const float* __restrict__ bvec,
                                               const float* __restrict__ avec,
                                               float* __restrict__ inp,
                                               float* __restrict__ evec,
                                               float* __restrict__ hsumv) {
    __shared__ bf16x8 Ash[320];    // (g*80 + r)
    __shared__ bf16x8 Bsh[1024];   // (g*256 + n)
    __shared__ float ePart[4][80];
    __shared__ float hPart[4][80];
    int tid = threadIdx.x, wid = tid >> 6, lane = tid & 63;
    int l15 = lane & 15, l4 = lane >> 4;
    int mb = blockIdx.x;

    f32x4 acc[4][5];
#pragma unroll
    for (int c = 0; c < 4; ++c)
#pragma unroll
        for (int rt = 0; rt < 5; ++rt) acc[c][rt] = f32x4{0.f, 0.f, 0.f, 0.f};

    for (int kb = 0; kb < 8; ++kb) {
        for (int rr = wid; rr < 5; rr += 4) {
            int c = rr * 64 + lane;
            int g = c / 80, r = c - g * 80;
            gl_lds16(XG + ((kb * 4 + g) * 10000 + mb * 80 + r), (char*)Ash + rr * 1024);
        }
        for (int rr = wid; rr < 16; rr += 4)
            gl_lds16(WG + kb * 1024 + rr * 64 + lane, (char*)Bsh + rr * 1024);
        __syncthreads();

        bf16x8 af[5];
#pragma unroll
        for (int rt = 0; rt < 5; ++rt) af[rt] = Ash[l4 * 80 + rt * 16 + l15];
#pragma unroll
        for (int c = 0; c < 4; ++c) {
            bf16x8 bf = Bsh[l4 * 256 + (wid * 4 + c) * 16 + l15];
#pragma unroll
            for (int rt = 0; rt < 5; ++rt)
                acc[c][rt] = __builtin_amdgcn_mfma_f32_16x16x32_bf16(af[rt], bf, acc[c][rt], 0, 0, 0);
        }
        __syncthreads();
    }

    float pe[5][4], ph[5][4];
#pragma unroll
    for (int rt = 0; rt < 5; ++rt)
#pragma unroll
        for (int rg = 0; rg < 4; ++rg) { pe[rt][rg] = 0.f; ph[rt][rg] = 0.f; }

#pragma unroll
    for (int c = 0; c < 4; ++c) {
        int col = (wid * 4 + c) * 16 + l15;
        float av = avec[col];
        float bv = bvec[col];
#pragma unroll
        for (int rt = 0; rt < 5; ++rt) {
#pragma unroll
            for (int rg = 0; rg < 4; ++rg) {
                int row = mb * 80 + rt * 16 + l4 * 4 + rg;
                float v = acc[c][rt][rg];            // inp excludes bias (per reference)
                inp[row * 256 + col] = v;
                float h = tanhf(v + bv);
                pe[rt][rg] += h * av;
                ph[rt][rg] += h;
            }
        }
    }
#pragma unroll
    for (int rt = 0; rt < 5; ++rt) {
#pragma unroll
        for (int rg = 0; rg < 4; ++rg) {
            float se = pe[rt][rg], sh = ph[rt][rg];
#pragma unroll
            for (int m = 1; m < 16; m <<= 1) {
                se += __shfl_xor(se, m);
                sh += __shfl_xor(sh, m);
            }
            if (l15 == 0) {
                int lr = rt * 16 + l4 * 4 + rg;   // 0..79
                ePart[wid][lr] = se;
                hPart[wid][lr] = sh;
            }
        }
    }
    __syncthreads();
    if (tid < 80) {
        float e = ePart[0][tid] + ePart[1][tid] + ePart[2][tid] + ePart[3][tid];
        float h = hPart[0][tid] + hPart[1][tid] + hPart[2][tid] + hPart[3][tid];
        evec[mb * 80 + tid] = e;
        hsumv[mb * 80 + tid] = h;
    }
}

// ---------------- K2: global max of e over valid nodes, then g = exp(e-gmax) ----------------
__global__ __launch_bounds__(1024) void k_softmax_g(const float* __restrict__ evec,
                                                    const float* __restrict__ hsumv,
                                                    float* __restrict__ gv) {
    __shared__ float red[1024];
    int tid = threadIdx.x;
    float m = -3.0e38f;
    for (int i = tid; i < NN; i += 1024)
        if (hsumv[i] != 0.0f) m = fmaxf(m, evec[i]);
    red[tid] = m;
    __syncthreads();
    for (int s = 512; s > 0; s >>= 1) {
        if (tid < s) red[tid] = fmaxf(red[tid], red[tid + s]);
        __syncthreads();
    }
    float gmax = red[0];
    if (gmax < -1.0e37f) gmax = 0.0f;
    for (int i = tid; i < 10016; i += 1024) {
        float g = 0.0f;
        if (i < NN && hsumv[i] != 0.0f) g = expf(evec[i] - gmax);
        gv[i] = g;
    }
}

// ---------------- K3: build YG = [kb][oct][col] bf16 chunks for 32x32 MFMA B ----------------
// chunk c = oct*288 + n holds Y[kb*32 + oct*8 + j][n]; col 256 = g; cols 257..287 = 0.
// grid 320: kb >= 313 hits the k<NN guard everywhere -> zero pads.
__global__ __launch_bounds__(256) void k_build_yg(const float* __restrict__ inp,
                                                  const float* __restrict__ gv,
                                                  bf16x8* __restrict__ YG) {
    int kb = blockIdx.x;   // 0..319
    for (int c = threadIdx.x; c < 1152; c += 256) {
        int oct = c / 288, n = c - oct * 288;
        int k0 = kb * 32 + oct * 8;
        bf16x8 v;
#pragma unroll
        for (int j = 0; j < 8; ++j) {
            int k = k0 + j;
            float val = 0.0f;
            if (k < NN) {
                float gk = gv[k];
                if (n < 256) val = gk * inp[k * 256 + n];
                else if (n == 256) val = gk;
            }
            v[j] = (__bf16)val;
        }
        YG[kb * 1152 + c] = v;
    }
}

// ---- int32 {0,1} pair-of-int4 -> bf16x8 {0,1} fragment ----
__device__ __forceinline__ bf16x8 cvt_adj(int4 a, int4 b) {
    union { bf16x8 v; unsigned int u[4]; } r;
    r.u[0] = (a.x > 0 ? 0x3F80u : 0u) | (a.y > 0 ? 0x3F800000u : 0u);
    r.u[1] = (a.z > 0 ? 0x3F80u : 0u) | (a.w > 0 ? 0x3F800000u : 0u);
    r.u[2] = (b.x > 0 ? 0x3F80u : 0u) | (b.y > 0 ? 0x3F800000u : 0u);
    r.u[3] = (b.z > 0 ? 0x3F80u : 0u) | (b.w > 0 ? 0x3F800000u : 0u);
    return r.v;
}

// ---------------- K4: num_kc = adj @ Y  (32x32x16 MFMA: halves LDS traffic + instr count) ----------------
// The 13-round invariant (~150us) tracked the one constant: 16x16x32 shape -> fixed
// ~47us/CU of ds_read_b128 (1KB per 16K-FLOP MFMA) + ~110 instr/step on the in-order
// wave path. 32x32x16 doubles FLOP/instr and FLOP/LDS-byte: 18 MFMA + 18 ds_read per
// wave-step (was 34+34 per equivalent K). Skeleton = proven R3/R11: BM=128, 4 waves x
// 32 rows (row = lane&31, k = (lane>>5)*8+j — 32-wide analog of the verified 16x16 A
// layout), 9 col-tiles of 32 (Y padded to 288), BK=32, 2-buffer LDS via gl_lds,
// counted end-of-step vmcnt(4) (drains own stage, keeps 4 A-loads in flight),
// bijective kc-major XCD swizzle. C/D per m74/m101: col=lane&31,
// row=(reg&3)+8*(reg>>2)+4*(lane>>5).
__global__ __launch_bounds__(256, 2) void k_attn_gemm(const int* __restrict__ adj,
                                                      const bf16x8* __restrict__ YG,
                                                      float* __restrict__ pnum) {
    __shared__ bf16x8 Bsh[2][1152];   // double-buffered 32x288 bf16 tiles (36864 B)
    int tid = threadIdx.x, wid = tid >> 6, lane = tid & 63;
    int l31 = lane & 31, l5 = lane >> 5;

    // bijective kc-major XCD swizzle (m204): 474 = 8*59 + 2
    int orig = blockIdx.x;
    const int nwg = MB2 * KSPLIT, q = nwg >> 3, r = nwg & 7;
    int x = orig & 7, o = orig >> 3;
    int logical = (x < r ? x * (q + 1) : r * (q + 1) + (x - r) * q) + o;
    int kc = logical / MB2, mb = logical % MB2;   // kc-major: <=2 kc slices per XCD
    int s0 = (kc * KSTEPS) / KSPLIT, s1 = ((kc + 1) * KSTEPS) / KSPLIT;

    // A addressing: wave owns rows mb*128 + wid*32 .. +31; lane row = l31, k-oct = l5
    int rowA = mb * 128 + wid * 32 + l31;
    const int* pR = adj + (size_t)min(rowA, NN - 1) * 10000;

    f32x16 acc[9];
#pragma unroll
    for (int ct = 0; ct < 9; ++ct)
#pragma unroll
        for (int i = 0; i < 16; ++i) acc[ct][i] = 0.f;

    int4 aA[4];   // k-chunk0: [0],[1]; k-chunk1: [2],[3] — reloaded in place 1 step ahead

    auto stageB = [&](int sTile, int bufIdx) {   // 18 gl_lds block-wide (wid0/1: 5, wid2/3: 4)
        const bf16x8* src = YG + (size_t)sTile * 1152;
        char* dst = (char*)&Bsh[bufIdx][0];
#pragma unroll
        for (int i = 0; i < 5; ++i) {
            int rr = wid + i * 4;
            if (rr < 18) gl_lds16(src + rr * 64 + lane, dst + rr * 1024);
        }
    };
    auto loadA = [&](int sTile) {
        int kk0 = min(sTile * 32 + l5 * 8, 9992);        // clamp safe: B is 0 for k>=NN
        int kk1 = min(sTile * 32 + 16 + l5 * 8, 9992);
        const int4* p0 = (const int4*)(pR + kk0);
        const int4* p1 = (const int4*)(pR + kk1);
        aA[0] = p0[0]; aA[1] = p0[1]; aA[2] = p1[0]; aA[3] = p1[1];
    };
    auto compute = [&](bf16x8 fa0, bf16x8 fa1, int b) {
#pragma unroll
        for (int ct = 0; ct < 9; ++ct) {
            bf16x8 fb0 = Bsh[b][(l5) * 288 + ct * 32 + l31];          // k-chunk 0: octs 0,1
            acc[ct] = __builtin_amdgcn_mfma_f32_32x32x16_bf16(fa0, fb0, acc[ct], 0, 0, 0);
            bf16x8 fb1 = Bsh[b][(2 + l5) * 288 + ct * 32 + l31];      // k-chunk 1: octs 2,3
            acc[ct] = __builtin_amdgcn_mfma_f32_32x32x16_bf16(fa1, fb1, acc[ct], 0, 0, 0);
        }
    };

    // ---- prologue: stage B(s0), issue A(s0) ----
    stageB(s0, 0);
    __builtin_amdgcn_sched_barrier(0);
    loadA(s0);
    asm volatile("s_waitcnt vmcnt(4)" ::: "memory");   // drain own B(s0) stage; keep A(s0)
    __builtin_amdgcn_s_barrier();

    // ---- main loop: stage B(s+1); cvt A(s); reload A(s+1) in place; 18 MFMA; counted wait ----
    int buf = 0;
    for (int s = s0; s < s1 - 1; ++s) {
        stageB(s + 1, buf ^ 1);
        __builtin_amdgcn_sched_barrier(0);
        bf16x8 fa0 = cvt_adj(aA[0], aA[1]);
        bf16x8 fa1 = cvt_adj(aA[2], aA[3]);
        loadA(s + 1);                                   // WAR: ordered after cvt reads
        __builtin_amdgcn_sched_barrier(0);
        compute(fa0, fa1, buf);
        asm volatile("s_waitcnt vmcnt(4)" ::: "memory");  // drain own B(s+1); keep A(s+1)
        __builtin_amdgcn_s_barrier();
        buf ^= 1;
    }
    // tail step s1-1: B staged + barrier'd; A in flight (compiler inserts its wait)
    {
        bf16x8 fa0 = cvt_adj(aA[0], aA[1]);
        bf16x8 fa1 = cvt_adj(aA[2], aA[3]);
        compute(fa0, fa1, buf);
    }

    // ---- epilogue: plain stores; C row = (reg&3)+8*(reg>>2)+4*l5, col = ct*32+l31 ----
    float* base = pnum + (size_t)kc * 10000 * 272;
    int r0 = mb * 128 + wid * 32;
#pragma unroll
    for (int ct = 0; ct < 9; ++ct) {
        int col = ct * 32 + l31;
        if (col < 272) {
#pragma unroll
            for (int rg = 0; rg < 16; ++rg) {
                int row = r0 + (rg & 3) + 8 * (rg >> 2) + 4 * l5;
                if (row < NN) base[(size_t)row * 272 + col] = acc[ct][rg];
            }
        }
    }
}

// ---------------- K5: out = (sum_kc num_kc) / max(sum_kc den_kc, 1e-30) ----------------
__global__ __launch_bounds__(256) void k_finalize(const float* __restrict__ pnum,
                                                  float* __restrict__ out) {
    int idx = blockIdx.x * 256 + threadIdx.x;   // 0..639999 (float4 units)
    int i = idx >> 6, q = idx & 63;
    float4 sv = {0.f, 0.f, 0.f, 0.f};
    float den = 0.f;
#pragma unroll
    for (int kc = 0; kc < KSPLIT; ++kc) {
        const float* row = pnum + ((size_t)kc * 10000 + i) * 272;
        float4 v = ((const float4*)row)[q];
        sv.x += v.x; sv.y += v.y; sv.z += v.z; sv.w += v.w;
        den += row[256];
    }
    float r = 1.0f / fmaxf(den, 1e-30f);
    float4 o;
    o.x = sv.x * r; o.y = sv.y * r; o.z = sv.z * r; o.w = sv.w * r;
    ((float4*)(out + (size_t)i * 256))[q] = o;
}

extern "C" void kernel_launch(void* const* d_in, const int* in_sizes, int n_in,
                              void* d_out, int out_size, void* d_ws, size_t ws_size,
                              hipStream_t stream) {
    const float* X    = (const float*)d_in[0];
    const int*   adj  = (const int*)d_in[1];
    const float* W    = (const float*)d_in[3];
    const float* bvec = (const float*)d_in[4];
    const float* avec = (const float*)d_in[5];
    float* out = (float*)d_out;

    char* ws = (char*)d_ws;
    bf16x8* XG   = (bf16x8*)(ws + XG_OFF);
    bf16x8* WG   = (bf16x8*)(ws + WG_OFF);
    float*  inp  = (float*)(ws + INP_OFF);
    float*  evec = (float*)(ws + E_OFF);
    float*  hsv  = (float*)(ws + HS_OFF);
    float*  gv   = (float*)(ws + G_OFF);
    bf16x8* YG   = (bf16x8*)(ws + YG_OFF);
    float*  pnum = (float*)(ws + PN_OFF);

    k_build_xg<<<1250, 256, 0, stream>>>(X, XG);
    k_build_wg<<<32, 256, 0, stream>>>(W, WG);
    k_gemm1<<<125, 256, 0, stream>>>(XG, WG, bvec, avec, inp, evec, hsv);
    k_softmax_g<<<1, 1024, 0, stream>>>(evec, hsv, gv);
    k_build_yg<<<320, 256, 0, stream>>>(inp, gv, YG);
    k_attn_gemm<<<MB2 * KSPLIT, 256, 0, stream>>>(adj, YG, pnum);
    k_finalize<<<2500, 256, 0, stream>>>(pnum, out);
}

// Round 15
// 174.814 us; speedup vs baseline: 1.1666x; 1.1247x over previous
//
#include <hip/hip_runtime.h>
#include <hip/hip_bf16.h>
#include <cstdint>
#include <cstddef>

// Problem constants (shapes fixed by the reference)
#define NN      10000      // nodes (M == N == 10000)
#define DD      256        // feature dim
#define KSTEPS  313        // ceil(10016/32) K-steps of 32
#define MB2     79         // ceil(10000/128) m-blocks for big GEMM (BM=128)
#define KSPLIT  6          // 79*6 = 474 blocks, 2/CU

typedef __bf16 bf16x8 __attribute__((ext_vector_type(8)));
typedef float  f32x4  __attribute__((ext_vector_type(4)));

// ---- workspace layout (bytes) ----
#define XG_OFF   0ull
#define XG_SIZE  (32ull * 10000 * 16)        // [q=kb*4+g][row] 16B chunks (bf16 X, MFMA-A layout)
#define WG_OFF   (XG_OFF + XG_SIZE)
#define WG_SIZE  (32ull * 256 * 16)          // [q][n] chunks (bf16 W, MFMA-B layout)
#define INP_OFF  (WG_OFF + WG_SIZE)
#define INP_SIZE (10000ull * 256 * 4)        // inp = X@W, f32
#define E_OFF    (INP_OFF + INP_SIZE)
#define E_SIZE   (10016ull * 4)
#define HS_OFF   (E_OFF + E_SIZE)
#define HS_SIZE  (10016ull * 4)
#define GM_OFF   (HS_OFF + HS_SIZE)          // 1 uint: monotonic-mapped global max
#define GM_SIZE  (256ull)
#define YG_OFF   (GM_OFF + GM_SIZE)          // 256B aligned
#define YG_SIZE  (318ull * 1088 * 16)        // [kb32][chunk]; kb 313..317 zero pads
#define PN_OFF   (YG_OFF + YG_SIZE)
#define PN_SIZE  ((size_t)KSPLIT * 10000 * 272 * 4)  // per-kc partials: 256 numer cols + den at col 256

// async global(16B) -> LDS copy; dest = wave-uniform base + lane*16
__device__ __forceinline__ void gl_lds16(const void* g, void* lds) {
    __builtin_amdgcn_global_load_lds(
        (const __attribute__((address_space(1))) unsigned int*)g,
        (__attribute__((address_space(3))) unsigned int*)lds,
        16, 0, 0);
}

// ---------------- K0: build XG + WG, init gmaxU (fused prep) ----------------
// blocks 0..1249: XG (bf16 X in MFMA-A chunk layout: chunk q=kb*4+g holds
// X[row][q*8..q*8+7] at XG[q*10000+row]). blocks 1250..1281: WG (entry q*256+n
// holds W[q*8+j][n]).
__global__ __launch_bounds__(256) void k_prep(const float* __restrict__ X,
                                              bf16x8* __restrict__ XG,
                                              const float* __restrict__ W,
                                              bf16x8* __restrict__ WG,
                                              unsigned int* __restrict__ gmaxU) {
    int b = blockIdx.x;
    if (b < 1250) {
        int idx = b * 256 + threadIdx.x;   // 0..319999
        int row = idx >> 5;
        int q   = idx & 31;
        const float* src = X + row * 256 + q * 8;
        bf16x8 v;
#pragma unroll
        for (int j = 0; j < 8; ++j) v[j] = (__bf16)src[j];
        XG[q * 10000 + row] = v;
    } else {
        int e = (b - 1250) * 256 + threadIdx.x;   // 0..8191
        int q = e >> 8;
        int n = e & 255;
        bf16x8 v;
#pragma unroll
        for (int j = 0; j < 8; ++j) v[j] = (__bf16)W[(q * 8 + j) * 256 + n];
        WG[e] = v;
        if (b == 1250 && threadIdx.x == 0) *gmaxU = 0u;   // maps below any real float
    }
}

// ---------------- K1: inp = X@W (MFMA), fused tanh/e/hsum + block gmax atomicMax ----------------
__global__ __launch_bounds__(256) void k_gemm1(const bf16x8* __restrict__ XG,
                                               const bf16x8* __restrict__ WG,
                                               const float* __restrict__ bvec,
                                               const float* __restrict__ avec,
                                               float* __restrict__ inp,
                                               float* __restrict__ evec,
                                               float* __restrict__ hsumv,
                                               unsigned int* __restrict__ gmaxU) {
    __shared__ bf16x8 Ash[320];    // (g*80 + r)
    __shared__ bf16x8 Bsh[1024];   // (g*256 + n)
    __shared__ float ePart[4][80];
    __shared__ float hPart[4][80];
    int tid = threadIdx.x, wid = tid >> 6, lane = tid & 63;
    int l15 = lane & 15, l4 = lane >> 4;
    int mb = blockIdx.x;

    f32x4 acc[4][5];
#pragma unroll
    for (int c = 0; c < 4; ++c)
#pragma unroll
        for (int rt = 0; rt < 5; ++rt) acc[c][rt] = f32x4{0.f, 0.f, 0.f, 0.f};

    for (int kb = 0; kb < 8; ++kb) {
        for (int rr = wid; rr < 5; rr += 4) {
            int c = rr * 64 + lane;
            int g = c / 80, r = c - g * 80;
            gl_lds16(XG + ((kb * 4 + g) * 10000 + mb * 80 + r), (char*)Ash + rr * 1024);
        }
        for (int rr = wid; rr < 16; rr += 4)
            gl_lds16(WG + kb * 1024 + rr * 64 + lane, (char*)Bsh + rr * 1024);
        __syncthreads();

        bf16x8 af[5];
#pragma unroll
        for (int rt = 0; rt < 5; ++rt) af[rt] = Ash[l4 * 80 + rt * 16 + l15];
#pragma unroll
        for (int c = 0; c < 4; ++c) {
            bf16x8 bf = Bsh[l4 * 256 + (wid * 4 + c) * 16 + l15];
#pragma unroll
            for (int rt = 0; rt < 5; ++rt)
                acc[c][rt] = __builtin_amdgcn_mfma_f32_16x16x32_bf16(af[rt], bf, acc[c][rt], 0, 0, 0);
        }
        __syncthreads();
    }

    float pe[5][4], ph[5][4];
#pragma unroll
    for (int rt = 0; rt < 5; ++rt)
#pragma unroll
        for (int rg = 0; rg < 4; ++rg) { pe[rt][rg] = 0.f; ph[rt][rg] = 0.f; }

#pragma unroll
    for (int c = 0; c < 4; ++c) {
        int col = (wid * 4 + c) * 16 + l15;
        float av = avec[col];
        float bv = bvec[col];
#pragma unroll
        for (int rt = 0; rt < 5; ++rt) {
#pragma unroll
            for (int rg = 0; rg < 4; ++rg) {
                int row = mb * 80 + rt * 16 + l4 * 4 + rg;
                float v = acc[c][rt][rg];            // inp excludes bias (per reference)
                inp[row * 256 + col] = v;
                float h = tanhf(v + bv);
                pe[rt][rg] += h * av;
                ph[rt][rg] += h;
            }
        }
    }
#pragma unroll
    for (int rt = 0; rt < 5; ++rt) {
#pragma unroll
        for (int rg = 0; rg < 4; ++rg) {
            float se = pe[rt][rg], sh = ph[rt][rg];
#pragma unroll
            for (int m = 1; m < 16; m <<= 1) {
                se += __shfl_xor(se, m);
                sh += __shfl_xor(sh, m);
            }
            if (l15 == 0) {
                int lr = rt * 16 + l4 * 4 + rg;   // 0..79
                ePart[wid][lr] = se;
                hPart[wid][lr] = sh;
            }
        }
    }
    __syncthreads();
    if (tid < 80) {
        float e = ePart[0][tid] + ePart[1][tid] + ePart[2][tid] + ePart[3][tid];
        float h = hPart[0][tid] + hPart[1][tid] + hPart[2][tid] + hPart[3][tid];
        evec[mb * 80 + tid] = e;
        hsumv[mb * 80 + tid] = h;
        ePart[0][tid] = (h != 0.0f) ? e : -3.0e38f;   // scratch for block max (after last read)
    }
    __syncthreads();
    if (tid == 0) {
        float m = -3.0e38f;
        for (int i = 0; i < 80; ++i) m = fmaxf(m, ePart[0][i]);
        if (m > -2.9e38f) {
            unsigned int b = __float_as_uint(m);
            unsigned int u = (b & 0x80000000u) ? ~b : (b | 0x80000000u);   // monotonic map
            atomicMax(gmaxU, u);
        }
    }
}

// ---------------- K3: build YG (g = exp(e-gmax) on the fly; pre-chunked bf16 B tiles) ----------------
// grid 318: kb >= 313 hits the k<NN guard everywhere -> zero pads
__global__ __launch_bounds__(256) void k_build_yg(const float* __restrict__ inp,
                                                  const float* __restrict__ evec,
                                                  const float* __restrict__ hsumv,
                                                  const unsigned int* __restrict__ gmaxU,
                                                  bf16x8* __restrict__ YG) {
    __shared__ float gsh[32];
    int kb = blockIdx.x;   // 0..317
    if (threadIdx.x < 32) {
        unsigned int gu = *gmaxU;
        float gmax = 0.0f;
        if (gu != 0u)
            gmax = (gu & 0x80000000u) ? __uint_as_float(gu ^ 0x80000000u)
                                      : __uint_as_float(~gu);
        int k = kb * 32 + threadIdx.x;
        float g = 0.0f;
        if (k < NN && hsumv[k] != 0.0f) g = expf(evec[k] - gmax);
        gsh[threadIdx.x] = g;
    }
    __syncthreads();
    for (int c = threadIdx.x; c < 1088; c += 256) {
        int gq = c / 272, n = c - gq * 272;
        int j0 = gq * 8;
        bf16x8 v;
#pragma unroll
        for (int j = 0; j < 8; ++j) {
            int k = kb * 32 + j0 + j;
            float val = 0.0f;
            if (k < NN) {
                float gk = gsh[j0 + j];
                if (n < 256) val = gk * inp[k * 256 + n];
                else if (n == 256) val = gk;
            }
            v[j] = (__bf16)val;
        }
        YG[kb * 1088 + c] = v;
    }
}

// ---- int32 {0,1} pair-of-int4 -> bf16x8 {0,1} fragment ----
__device__ __forceinline__ bf16x8 cvt_adj(int4 a, int4 b) {
    union { bf16x8 v; unsigned int u[4]; } r;
    r.u[0] = (a.x > 0 ? 0x3F80u : 0u) | (a.y > 0 ? 0x3F800000u : 0u);
    r.u[1] = (a.z > 0 ? 0x3F80u : 0u) | (a.w > 0 ? 0x3F800000u : 0u);
    r.u[2] = (b.x > 0 ? 0x3F80u : 0u) | (b.y > 0 ? 0x3F800000u : 0u);
    r.u[3] = (b.z > 0 ? 0x3F80u : 0u) | (b.w > 0 ? 0x3F800000u : 0u);
    return r.v;
}

// ---------------- K4: num_kc = adj @ Y  (R11 all-async kernel, verbatim — best measured) ----------------
__global__ __launch_bounds__(256, 2) void k_attn_gemm(const int* __restrict__ adj,
                                                      const bf16x8* __restrict__ YG,
                                                      float* __restrict__ pnum) {
    __shared__ int    Ash[2][4096];   // [buf][row*32 + k'] ints: 2 x 16 KB (swizzled 16B chunks)
    __shared__ bf16x8 Bsh[2][1088];   // [buf] 32x272 bf16 tiles: 2 x 17 KB
    int tid = threadIdx.x, wid = tid >> 6, lane = tid & 63;
    int l15 = lane & 15, l4 = lane >> 4;

    // bijective kc-major XCD swizzle (m204): 474 = 8*59 + 2; <=2 YG slices per XCD L2
    int orig = blockIdx.x;
    const int nwg = MB2 * KSPLIT, q = nwg >> 3, r = nwg & 7;
    int x = orig & 7, o = orig >> 3;
    int logical = (x < r ? x * (q + 1) : r * (q + 1) + (x - r) * q) + o;
    int kc = logical / MB2, mb = logical % MB2;
    int s0 = (kc * KSTEPS) / KSPLIT, s1 = ((kc + 1) * KSTEPS) / KSPLIT;

    // A staging precompute: 16 gl_lds instrs block-wide (4 per wave); LDS[row][p] =
    // global chunk (p ^ (row&7)) -> staging line-coalesced, reads conflict-free.
    const int* aSrc[4];
    int aLim[4];
#pragma unroll
    for (int i = 0; i < 4; ++i) {
        int c = (wid + i * 4) * 64 + lane;
        int row = c >> 3;
        int p = c & 7;
        int ck4 = (p ^ (row & 7)) * 4;               // global int offset within step span
        int grow = min(mb * 128 + row, NN - 1);
        aSrc[i] = adj + (size_t)grow * 10000 + ck4;
        aLim[i] = 9996 - ck4;                        // min(s*32, aLim) keeps all reads in row
    }

    f32x4 acc[2][17];
#pragma unroll
    for (int t = 0; t < 2; ++t)
#pragma unroll
        for (int ct = 0; ct < 17; ++ct) acc[t][ct] = f32x4{0.f, 0.f, 0.f, 0.f};

    auto stageA = [&](int sTile, int bufIdx) {
        int kk = sTile * 32;
        char* dst = (char*)&Ash[bufIdx][0];
#pragma unroll
        for (int i = 0; i < 4; ++i)
            gl_lds16(aSrc[i] + min(kk, aLim[i]), dst + (wid + i * 4) * 1024);
    };
    auto stageB = [&](int sTile, int bufIdx) {
        const bf16x8* src = YG + (size_t)sTile * 1088;
        char* dst = (char*)&Bsh[bufIdx][0];
#pragma unroll
        for (int i = 0; i < 5; ++i) {
            int rr = wid + i * 4;
            if (rr < 17) gl_lds16(src + rr * 64 + lane, dst + rr * 1024);  // wave0: 5, others: 4
        }
    };

    // A-frag read offsets (swizzled): row = wid*32 + rt*16 + l15 (row&7 == l15&7)
    int xr = l15 & 7;
    int p0 = (2 * l4) ^ xr;                 // LDS chunk holding global chunk 2*l4
    int rowA0 = wid * 32 + l15;             // rt=0 row; rt=1 adds 16 (doesn't change &7)

    // ---- prologue ----
    stageA(s0, 0);
    stageB(s0, 0);
    __syncthreads();

    // ---- main loop: one barrier per step, everything async ----
    int buf = 0;
    for (int s = s0; s < s1; ++s) {
        if (s + 1 < s1) {
            stageA(s + 1, buf ^ 1);
            stageB(s + 1, buf ^ 1);
        }
        const int* ab = &Ash[buf][0];
        int4 v00 = *(const int4*)(ab + rowA0 * 32 + p0 * 4);
        int4 v01 = *(const int4*)(ab + rowA0 * 32 + (p0 ^ 1) * 4);
        int4 v10 = *(const int4*)(ab + (rowA0 + 16) * 32 + p0 * 4);
        int4 v11 = *(const int4*)(ab + (rowA0 + 16) * 32 + (p0 ^ 1) * 4);
        bf16x8 fa0 = cvt_adj(v00, v01);
        bf16x8 fa1 = cvt_adj(v10, v11);
#pragma unroll
        for (int ct = 0; ct < 17; ++ct) {
            bf16x8 fb = Bsh[buf][l4 * 272 + ct * 16 + l15];
            acc[0][ct] = __builtin_amdgcn_mfma_f32_16x16x32_bf16(fa0, fb, acc[0][ct], 0, 0, 0);
            acc[1][ct] = __builtin_amdgcn_mfma_f32_16x16x32_bf16(fa1, fb, acc[1][ct], 0, 0, 0);
        }
        __syncthreads();
        buf ^= 1;
    }

    // ---- epilogue: plain stores to per-kc partial buffer ----
    float* base = pnum + (size_t)kc * 10000 * 272;
    int r0 = mb * 128 + wid * 32;
#pragma unroll
    for (int t = 0; t < 2; ++t) {
#pragma unroll
        for (int ct = 0; ct < 17; ++ct) {
            int col = ct * 16 + l15;
#pragma unroll
            for (int rg = 0; rg < 4; ++rg) {
                int row = r0 + t * 16 + l4 * 4 + rg;
                if (row < NN) base[(size_t)row * 272 + col] = acc[t][ct][rg];
            }
        }
    }
}

// ---------------- K5: out = (sum_kc num_kc) / max(sum_kc den_kc, 1e-30) ----------------
__global__ __launch_bounds__(256) void k_finalize(const float* __restrict__ pnum,
                                                  float* __restrict__ out) {
    int idx = blockIdx.x * 256 + threadIdx.x;   // 0..639999 (float4 units)
    int i = idx >> 6, q = idx & 63;
    float4 sv = {0.f, 0.f, 0.f, 0.f};
    float den = 0.f;
#pragma unroll
    for (int kc = 0; kc < KSPLIT; ++kc) {
        const float* row = pnum + ((size_t)kc * 10000 + i) * 272;
        float4 v = ((const float4*)row)[q];
        sv.x += v.x; sv.y += v.y; sv.z += v.z; sv.w += v.w;
        den += row[256];
    }
    float r = 1.0f / fmaxf(den, 1e-30f);
    float4 o;
    o.x = sv.x * r; o.y = sv.y * r; o.z = sv.z * r; o.w = sv.w * r;
    ((float4*)(out + (size_t)i * 256))[q] = o;
}

extern "C" void kernel_launch(void* const* d_in, const int* in_sizes, int n_in,
                              void* d_out, int out_size, void* d_ws, size_t ws_size,
                              hipStream_t stream) {
    const float* X    = (const float*)d_in[0];
    const int*   adj  = (const int*)d_in[1];
    const float* W    = (const float*)d_in[3];
    const float* bvec = (const float*)d_in[4];
    const float* avec = (const float*)d_in[5];
    float* out = (float*)d_out;

    char* ws = (char*)d_ws;
    bf16x8* XG   = (bf16x8*)(ws + XG_OFF);
    bf16x8* WG   = (bf16x8*)(ws + WG_OFF);
    float*  inp  = (float*)(ws + INP_OFF);
    float*  evec = (float*)(ws + E_OFF);
    float*  hsv  = (float*)(ws + HS_OFF);
    unsigned int* gmaxU = (unsigned int*)(ws + GM_OFF);
    bf16x8* YG   = (bf16x8*)(ws + YG_OFF);
    float*  pnum = (float*)(ws + PN_OFF);

    k_prep<<<1282, 256, 0, stream>>>(X, XG, W, WG, gmaxU);
    k_gemm1<<<125, 256, 0, stream>>>(XG, WG, bvec, avec, inp, evec, hsv, gmaxU);
    k_build_yg<<<318, 256, 0, stream>>>(inp, evec, hsv, gmaxU, YG);
    k_attn_gemm<<<MB2 * KSPLIT, 256, 0, stream>>>(adj, YG, pnum);
    k_finalize<<<2500, 256, 0, stream>>>(pnum, out);
}